// Round 12
// baseline (180.804 us; speedup 1.0000x reference)
//
#include <hip/hip_runtime.h>
#include <math.h>

// Problem constants (fixed by the reference):
#define BB 32     // batch
#define NN 128    // nodes
#define CC 16     // in_ch
#define OO 32     // out_ch
#define II 32     // in_dim
#define JJ 32     // out_dim
#define MM (NN*CC)  // 2048 input capsules per (b, out_ch)
#define WP (JJ+1)   // padded Ws row: 33 floats -> conflict-free for BOTH
                    // A (lanes on j, stride-WP rows) and Wv (lanes on i)
static constexpr float EPS_ = 1e-11f;

// SINGLE-KERNEL design (round 12): the transpose kernel is deleted; its
// ~60 us of dispatch+drain+overhead was co-dominant with k_route itself.
// Raw x[b][n][c][i] is loaded directly: thread (c,n4,s) holds
// rv[dn][iq] = x(b, n=n4*4+dn, c, i=s*16+iq*4..+3), a float4 of 4 i's.
// The C/U phases are component-re-indexed accordingly (same FLOPs):
//   C: p4[iq] += rv[dn][iq] * cf[dn]   (cf components = 4 n's)
//   U: r[dn]  += dot(rv[dn][iq], w4[iq])  -- w4 = f4 LDS reads of wv
// U's LDS reads drop 64 scalar -> 8 f4. W stays LDS-resident (132 KB,
// i-major, WP=33 conflict-free). VGPR wall (64) accepted: residual spill
// ~16 B/thread (~8 MB WRITE_SIZE) is cheaper than any workaround found
// in rounds 8-10.

// 16-slot reduce-scatter across lane bits 1..4 (n4 bits); returns the
// fully-reduced value for slot qf = this lane's bit-pattern.
__device__ __forceinline__ float rs16(float p[16], int l) {
  bool u2 = (l >> 1) & 1, u4 = (l >> 2) & 1, u8 = (l >> 3) & 1, u16 = (l >> 4) & 1;
  #pragma unroll
  for (int k = 0; k < 8; ++k) {
    float s0 = u2 ? p[k] : p[k + 8];
    float r0 = __shfl_xor(s0, 2);
    p[k] = (u2 ? p[k + 8] : p[k]) + r0;
  }
  #pragma unroll
  for (int k = 0; k < 4; ++k) {
    float s0 = u4 ? p[k] : p[k + 4];
    float r0 = __shfl_xor(s0, 4);
    p[k] = (u4 ? p[k + 4] : p[k]) + r0;
  }
  #pragma unroll
  for (int k = 0; k < 2; ++k) {
    float s0 = u8 ? p[k] : p[k + 2];
    float r0 = __shfl_xor(s0, 8);
    p[k] = (u8 ? p[k + 2] : p[k]) + r0;
  }
  {
    float s0 = u16 ? p[0] : p[1];
    float r0 = __shfl_xor(s0, 16);
    p[0] = (u16 ? p[1] : p[0]) + r0;
  }
  p[0] += __shfl_xor(p[0], 32);          // allreduce the last n4 bit
  return p[0];
}

// ---- the whole routing loop. Block per (b, o-pair). 1024 threads. ----
__global__ __launch_bounds__(1024, 4) void k_route(
    const float* __restrict__ x, const float* __restrict__ W,
    float* __restrict__ out) {
  int bid = blockIdx.x;
  int b = bid & 31, o0 = (bid >> 5) * 2;      // o-pair {o0, o0+1}
  int tid = threadIdx.x;

  __shared__ float Ws[CC * 2 * II * WP];            // 132 KB: W slice, padded
  __shared__ __align__(16) float bijL[2][CC][NN];   // 16 KB routing logits
  __shared__ __align__(16) float cw[2][CC][II];     // 4 KB: cxs in C/A, wv in Wv/U
  __shared__ float partA[2][CC][JJ];                // 4 KB
  __shared__ float vs[2][JJ];
  __shared__ float redM[CC][2], redE[CC][2];
  __shared__ float smx[2], srin[2];
  // total ~157 KB -> 1 block/CU

  // ---- stage W slice into LDS (once; W is iteration-invariant) ----
  {
    int q = tid & 7, r0 = tid >> 3;
    #pragma unroll
    for (int k = 0; k < 8; ++k) {
      int rowid = r0 + k * 128;                   // rowid = (c<<6)|(o<<5)|i
      int c = rowid >> 6, o = (rowid >> 5) & 1, i = rowid & 31;
      float4 v = *(const float4*)(W + ((((size_t)c * OO + o0 + o) * II + i) * JJ) + q * 4);
      float* dst = &Ws[rowid * WP + q * 4];       // coalesced 1KB/instr reads
      dst[0] = v.x; dst[1] = v.y; dst[2] = v.z; dst[3] = v.w;
    }
  }

  // x -> registers (once, raw layout): thread (c, n4, s) owns
  // n = n4*4..+3, i = s*16..+15; rv[dn][iq] = f4 of 4 i's.
  int l = tid & 63;
  int c = tid >> 6, n4 = l >> 1, s = l & 1;
  const float* xb = x + (size_t)b * NN * CC * II;
  float4 rv[4][4];
  #pragma unroll
  for (int dn = 0; dn < 4; ++dn)
    #pragma unroll
    for (int iq = 0; iq < 4; ++iq)
      rv[dn][iq] = *(const float4*)(xb + ((size_t)(n4 * 4 + dn) * CC + c) * II
                                       + s * 16 + iq * 4);

  {  // init: bijL = 0; smx=0, srin=1/MM makes iter-0 coef exactly uniform
    int o = tid >> 9, ci = (tid >> 5) & 15, m4i = tid & 31;
    *(float4*)(&bijL[o][ci][m4i * 4]) = make_float4(0.f, 0.f, 0.f, 0.f);
    if (tid < 2) { smx[tid] = 0.f; srin[tid] = 1.0f / (float)MM; }
  }
  __syncthreads();

  for (int it = 0; it < 3; ++it) {
    // --- C: cw[o][c][i] = sum_n coef(o,c,n)*x(c,n,i); coef recomputed
    //     from bijL (o's sequential to bound register pressure) ---
    {
      int qf = ((l >> 1) & 1) * 8 + ((l >> 2) & 1) * 4
             + ((l >> 3) & 1) * 2 + ((l >> 4) & 1);
      #pragma unroll
      for (int o = 0; o < 2; ++o) {
        float4 bb = *(const float4*)(&bijL[o][c][n4 * 4]);
        float m = smx[o], ri = srin[o];
        float cf0 = __expf(bb.x - m) * ri, cf1 = __expf(bb.y - m) * ri;
        float cf2 = __expf(bb.z - m) * ri, cf3 = __expf(bb.w - m) * ri;
        float p[16];
        #pragma unroll
        for (int iq = 0; iq < 4; ++iq) {
          float4 p4;
          p4.x = rv[0][iq].x*cf0 + rv[1][iq].x*cf1 + rv[2][iq].x*cf2 + rv[3][iq].x*cf3;
          p4.y = rv[0][iq].y*cf0 + rv[1][iq].y*cf1 + rv[2][iq].y*cf2 + rv[3][iq].y*cf3;
          p4.z = rv[0][iq].z*cf0 + rv[1][iq].z*cf1 + rv[2][iq].z*cf2 + rv[3][iq].z*cf3;
          p4.w = rv[0][iq].w*cf0 + rv[1][iq].w*cf1 + rv[2][iq].w*cf2 + rv[3][iq].w*cf3;
          p[iq * 4 + 0] = p4.x; p[iq * 4 + 1] = p4.y;
          p[iq * 4 + 2] = p4.z; p[iq * 4 + 3] = p4.w;
        }
        float r = rs16(p, l);
        if ((l & 32) == 0) cw[o][c][s * 16 + qf] = r;
      }
    }
    __syncthreads();

    // --- A: partA[o][c][j] = sum_i cw[o][c][i] * Ws[c,o,i,j]  (pure LDS) ---
    {
      int o = tid >> 9, cA = (tid >> 5) & 15, j = tid & 31;
      const float* wsp = &Ws[((cA * 2 + o) * II) * WP + j];
      float acc = 0.f;
      #pragma unroll 8
      for (int i = 0; i < II; ++i)
        acc += cw[o][cA][i] * wsp[i * WP];   // cw broadcast, Ws conflict-free
      partA[o][cA][j] = acc;
    }
    __syncthreads();

    // --- A-reduce + squash (final iter writes output) ---
    if (tid < 64) {
      int o = tid >> 5, j = tid & 31;
      float sA = 0.f;
      #pragma unroll
      for (int cR = 0; cR < CC; ++cR) sA += partA[o][cR][j];
      float msq = sA * sA;
      #pragma unroll
      for (int off = 16; off > 0; off >>= 1) msq += __shfl_xor(msq, off);
      float mag = sqrtf(msq) + EPS_;
      float a   = msq / (1.0f + msq);
      float vvq = a * sA / mag;
      if (it == 2) {
        int row = b * OO + (o0 + o);
        out[(size_t)row * JJ + j] = vvq;               // v_j: [B,1,O,J] flat
        if (j == 0) out[BB * OO * JJ + row] = a;       // a_j: [B,1,O,1] flat
      } else {
        vs[o][j] = vvq;
      }
    }
    if (it == 2) break;                   // uniform exit
    __syncthreads();

    // --- Wv: cw[o][c][i] = sum_j Ws[c,o,i,j] * vs[o][j]  (pure LDS) ---
    {
      int o = tid >> 9, cW = (tid >> 5) & 15, i = tid & 31;
      const float* wsr = &Ws[((cW * 2 + o) * II + i) * WP];
      float acc = 0.f;
      #pragma unroll 8
      for (int j = 0; j < JJ; ++j)
        acc += wsr[j] * vs[o][j];          // banks (i+j)%32: conflict-free
      cw[o][cW][i] = acc;                  // buffer now holds wv
    }
    __syncthreads();

    // --- U: bijL += x.wv (x from regs, wv via f4 reads); stats fused ---
    {
      float rn[2][4];                      // r per o per dn
      #pragma unroll
      for (int o = 0; o < 2; ++o) {
        rn[o][0] = 0.f; rn[o][1] = 0.f; rn[o][2] = 0.f; rn[o][3] = 0.f;
        #pragma unroll
        for (int iq = 0; iq < 4; ++iq) {
          float4 w4 = *(const float4*)(&cw[o][c][s * 16 + iq * 4]);  // b128
          #pragma unroll
          for (int dn = 0; dn < 4; ++dn)
            rn[o][dn] += rv[dn][iq].x * w4.x + rv[dn][iq].y * w4.y
                       + rv[dn][iq].z * w4.z + rv[dn][iq].w * w4.w;
        }
      }
      float4 ac0 = make_float4(rn[0][0], rn[0][1], rn[0][2], rn[0][3]);
      float4 ac1 = make_float4(rn[1][0], rn[1][1], rn[1][2], rn[1][3]);
      // combine i-halves across the s-pair
      ac0.x += __shfl_xor(ac0.x, 1); ac0.y += __shfl_xor(ac0.y, 1);
      ac0.z += __shfl_xor(ac0.z, 1); ac0.w += __shfl_xor(ac0.w, 1);
      ac1.x += __shfl_xor(ac1.x, 1); ac1.y += __shfl_xor(ac1.y, 1);
      ac1.z += __shfl_xor(ac1.z, 1); ac1.w += __shfl_xor(ac1.w, 1);
      float4 r = (s == 0) ? ac0 : ac1;              // lane s owns o=s
      float4 bb = *(const float4*)(&bijL[s][c][n4 * 4]);
      r.x += bb.x; r.y += bb.y; r.z += bb.z; r.w += bb.w;
      *(float4*)(&bijL[s][c][n4 * 4]) = r;

      // per-wave max partials (parity-preserving: offsets 2..32)
      float m4 = fmaxf(fmaxf(r.x, r.y), fmaxf(r.z, r.w));
      #pragma unroll
      for (int off = 2; off <= 32; off <<= 1) m4 = fmaxf(m4, __shfl_xor(m4, off));
      int wave = tid >> 6;
      if ((tid & 63) <= 1) redM[wave][s] = m4;      // lane 0: o=0, lane 1: o=1
      __syncthreads();
      float mo = redM[0][s];                        // every thread reduces locally
      #pragma unroll
      for (int w2 = 1; w2 < CC; ++w2) mo = fmaxf(mo, redM[w2][s]);
      float ex = __expf(r.x - mo), ey = __expf(r.y - mo),
            ez = __expf(r.z - mo), ew = __expf(r.w - mo);
      float e = ex + ey + ez + ew;
      #pragma unroll
      for (int off = 2; off <= 32; off <<= 1) e += __shfl_xor(e, off);
      if ((tid & 63) <= 1) redE[wave][s] = e;
      __syncthreads();
      if (tid < 2) {                                // stats for next C
        float ss = 0.f, mm = redM[0][tid];
        #pragma unroll
        for (int w2 = 0; w2 < CC; ++w2) ss += redE[w2][tid];
        #pragma unroll
        for (int w2 = 1; w2 < CC; ++w2) mm = fmaxf(mm, redM[w2][tid]);
        smx[tid]  = mm;
        srin[tid] = 1.0f / ss;
      }
    }
    __syncthreads();
  }
}

extern "C" void kernel_launch(void* const* d_in, const int* in_sizes, int n_in,
                              void* d_out, int out_size, void* d_ws, size_t ws_size,
                              hipStream_t stream) {
  const float* x = (const float*)d_in[0];   // [B,N,C,I]
  const float* W = (const float*)d_in[1];   // [C,O,I,J]
  (void)in_sizes; (void)n_in;               // d_in[2] = number_of_nodes (fixed 128)
  float* out = (float*)d_out; (void)out_size;
  (void)d_ws; (void)ws_size;                // no workspace needed anymore

  k_route<<<BB * (OO / 2), 1024, 0, stream>>>(x, W, out);
}

// Round 13
// 121.500 us; speedup vs baseline: 1.4881x; 1.4881x over previous
//
#include <hip/hip_runtime.h>
#include <math.h>

// Problem constants (fixed by the reference):
#define BB 32     // batch
#define NN 128    // nodes
#define CC 16     // in_ch
#define OO 32     // out_ch
#define II 32     // in_dim
#define JJ 32     // out_dim
#define MM (NN*CC)  // 2048 input capsules per (b, out_ch)
#define WP (JJ+1)   // padded Ws row: 33 floats -> conflict-free for BOTH
                    // A (lanes on j, stride-WP rows) and Wv (lanes on i)
static constexpr float EPS_ = 1e-11f;

// ROUND-13 = ROUND-11 REVERT + U-phase f4 LDS reads.
// Round-12 lessons: (a) raw-x rv[4][4] layout -> total spill (FETCH+WRITE
// ~400 MB, k_route 127 us) — the xT-based xv[16] layout with its ~16 B/
// thread spill is the right point on the curve; (b) the ~55 us total-vs-
// kernel gap is FIXED harness overhead (persisted with 1 dispatch), so
// k_transpose (~5 us) is cheap and stays.
//
// Design: block per (b, o-pair); x register-resident via xT (xv[16] f4);
// W LDS-resident (132 KB padded); coef recomputed from bijL each iter;
// zero global ops inside the loop. U now reads wv as 8 ds_read_b128
// (2-addr broadcast, conflict-free) instead of 64 ds_read_b32.

// ---- one-time transpose: xT[b][c][i][n] = x[b][n][c][i] ----
__global__ __launch_bounds__(1024) void k_transpose(
    const float* __restrict__ x, float* __restrict__ xT) {
  int b = blockIdx.x >> 4, c = blockIdx.x & 15;
  __shared__ __align__(16) float xsT[II][NN + 4];   // +4: f4-aligned padded rows
  int tid = threadIdx.x;
  {
    int n = tid >> 3, i4 = (tid & 7) * 4;
    float4 v = *(const float4*)(x + (((size_t)(b * NN + n)) * CC + c) * II + i4);
    xsT[i4 + 0][n] = v.x; xsT[i4 + 1][n] = v.y;
    xsT[i4 + 2][n] = v.z; xsT[i4 + 3][n] = v.w;
  }
  __syncthreads();
  {
    int i = tid >> 5, n4 = tid & 31;
    float4 v = *(const float4*)(&xsT[i][n4 * 4]);   // row stride 528 B, 16B-aligned
    ((float4*)(xT + ((size_t)(b * CC + c)) * II * NN))[tid] = v;
  }
}

// 16-slot reduce-scatter across lane bits 1..4 (n4 bits); returns the
// fully-reduced value for slot qf = this lane's bit-pattern.
__device__ __forceinline__ float rs16(float p[16], int l) {
  bool u2 = (l >> 1) & 1, u4 = (l >> 2) & 1, u8 = (l >> 3) & 1, u16 = (l >> 4) & 1;
  #pragma unroll
  for (int k = 0; k < 8; ++k) {
    float s0 = u2 ? p[k] : p[k + 8];
    float r0 = __shfl_xor(s0, 2);
    p[k] = (u2 ? p[k + 8] : p[k]) + r0;
  }
  #pragma unroll
  for (int k = 0; k < 4; ++k) {
    float s0 = u4 ? p[k] : p[k + 4];
    float r0 = __shfl_xor(s0, 4);
    p[k] = (u4 ? p[k + 4] : p[k]) + r0;
  }
  #pragma unroll
  for (int k = 0; k < 2; ++k) {
    float s0 = u8 ? p[k] : p[k + 2];
    float r0 = __shfl_xor(s0, 8);
    p[k] = (u8 ? p[k + 2] : p[k]) + r0;
  }
  {
    float s0 = u16 ? p[0] : p[1];
    float r0 = __shfl_xor(s0, 16);
    p[0] = (u16 ? p[1] : p[0]) + r0;
  }
  p[0] += __shfl_xor(p[0], 32);          // allreduce the last n4 bit
  return p[0];
}

// ---- the whole routing loop. Block per (b, o-pair). 1024 threads. ----
__global__ __launch_bounds__(1024, 4) void k_route(
    const float* __restrict__ xT, const float* __restrict__ W,
    float* __restrict__ out) {
  int bid = blockIdx.x;
  int b = bid & 31, o0 = (bid >> 5) * 2;      // o-pair {o0, o0+1}
  int tid = threadIdx.x;

  __shared__ float Ws[CC * 2 * II * WP];            // 132 KB: W slice, padded
  __shared__ __align__(16) float bijL[2][CC][NN];   // 16 KB routing logits
  __shared__ __align__(16) float cw[2][CC][II];     // 4 KB: cxs in C/A, wv in Wv/U
  __shared__ float partA[2][CC][JJ];                // 4 KB
  __shared__ float vs[2][JJ];
  __shared__ float redM[CC][2], redE[CC][2];
  __shared__ float smx[2], srin[2];
  // total ~157 KB -> 1 block/CU

  // ---- stage W slice into LDS (once; W is iteration-invariant) ----
  {
    int q = tid & 7, r0 = tid >> 3;
    #pragma unroll
    for (int k = 0; k < 8; ++k) {
      int rowid = r0 + k * 128;                   // rowid = (c<<6)|(o<<5)|i
      int c = rowid >> 6, o = (rowid >> 5) & 1, i = rowid & 31;
      float4 v = *(const float4*)(W + ((((size_t)c * OO + o0 + o) * II + i) * JJ) + q * 4);
      float* dst = &Ws[rowid * WP + q * 4];       // coalesced 1KB/instr reads
      dst[0] = v.x; dst[1] = v.y; dst[2] = v.z; dst[3] = v.w;
    }
  }

  // x -> registers (once): thread (c, n4, s) owns i=s*16..s*16+15, n=n4*4..+3
  int l = tid & 63;
  int c = tid >> 6, n4 = l >> 1, s = l & 1;
  const float4* xTb = (const float4*)(xT + (size_t)b * CC * II * NN);
  const float4* xp  = xTb + c * (II * NN / 4) + (s * 16) * (NN / 4) + n4;
  float4 xv[16];
  #pragma unroll
  for (int q = 0; q < 16; ++q) xv[q] = xp[q * (NN / 4)];  // 512B runs, coalesced

  {  // init: bijL = 0; smx=0, srin=1/MM makes iter-0 coef exactly uniform
    int o = tid >> 9, ci = (tid >> 5) & 15, m4i = tid & 31;
    *(float4*)(&bijL[o][ci][m4i * 4]) = make_float4(0.f, 0.f, 0.f, 0.f);
    if (tid < 2) { smx[tid] = 0.f; srin[tid] = 1.0f / (float)MM; }
  }
  __syncthreads();

  for (int it = 0; it < 3; ++it) {
    // --- C: cw[o][c][i] = sum_n coef(o,c,n)*x(c,n,i); coef recomputed
    //     from bijL (o's sequential to bound register pressure) ---
    {
      int qf = ((l >> 1) & 1) * 8 + ((l >> 2) & 1) * 4
             + ((l >> 3) & 1) * 2 + ((l >> 4) & 1);
      #pragma unroll
      for (int o = 0; o < 2; ++o) {
        float4 bb = *(const float4*)(&bijL[o][c][n4 * 4]);
        float m = smx[o], ri = srin[o];
        float cfx = __expf(bb.x - m) * ri, cfy = __expf(bb.y - m) * ri;
        float cfz = __expf(bb.z - m) * ri, cfw = __expf(bb.w - m) * ri;
        float p[16];
        #pragma unroll
        for (int q = 0; q < 16; ++q)
          p[q] = xv[q].x*cfx + xv[q].y*cfy + xv[q].z*cfz + xv[q].w*cfw;
        float r = rs16(p, l);
        if ((l & 32) == 0) cw[o][c][s * 16 + qf] = r;
      }
    }
    __syncthreads();

    // --- A: partA[o][c][j] = sum_i cw[o][c][i] * Ws[c,o,i,j]  (pure LDS) ---
    {
      int o = tid >> 9, cA = (tid >> 5) & 15, j = tid & 31;
      const float* wsp = &Ws[((cA * 2 + o) * II) * WP + j];
      float acc = 0.f;
      #pragma unroll 8
      for (int i = 0; i < II; ++i)
        acc += cw[o][cA][i] * wsp[i * WP];   // cw broadcast, Ws conflict-free
      partA[o][cA][j] = acc;
    }
    __syncthreads();

    // --- A-reduce + squash (final iter writes output) ---
    if (tid < 64) {
      int o = tid >> 5, j = tid & 31;
      float sA = 0.f;
      #pragma unroll
      for (int cR = 0; cR < CC; ++cR) sA += partA[o][cR][j];
      float msq = sA * sA;
      #pragma unroll
      for (int off = 16; off > 0; off >>= 1) msq += __shfl_xor(msq, off);
      float mag = sqrtf(msq) + EPS_;
      float a   = msq / (1.0f + msq);
      float vvq = a * sA / mag;
      if (it == 2) {
        int row = b * OO + (o0 + o);
        out[(size_t)row * JJ + j] = vvq;               // v_j: [B,1,O,J] flat
        if (j == 0) out[BB * OO * JJ + row] = a;       // a_j: [B,1,O,1] flat
      } else {
        vs[o][j] = vvq;
      }
    }
    if (it == 2) break;                   // uniform exit
    __syncthreads();

    // --- Wv: cw[o][c][i] = sum_j Ws[c,o,i,j] * vs[o][j]  (pure LDS) ---
    {
      int o = tid >> 9, cW = (tid >> 5) & 15, i = tid & 31;
      const float* wsr = &Ws[((cW * 2 + o) * II + i) * WP];
      float acc = 0.f;
      #pragma unroll 8
      for (int j = 0; j < JJ; ++j)
        acc += wsr[j] * vs[o][j];          // banks (i+j)%32: conflict-free
      cw[o][cW][i] = acc;                  // buffer now holds wv
    }
    __syncthreads();

    // --- U: bijL += x.wv; wv via 8 ds_read_b128 (2-addr broadcast);
    //     stats + smx/srin for next C, fused ---
    {
      float4 ac0 = make_float4(0.f,0.f,0.f,0.f);
      float4 ac1 = make_float4(0.f,0.f,0.f,0.f);
      #pragma unroll
      for (int iq = 0; iq < 4; ++iq) {
        float4 w40 = *(const float4*)(&cw[0][c][s * 16 + iq * 4]);
        float4 w41 = *(const float4*)(&cw[1][c][s * 16 + iq * 4]);
        // xv[iq*4+k] = f4 over n at i = s*16 + iq*4 + k
        float4 xa = xv[iq*4+0], xb2 = xv[iq*4+1], xc = xv[iq*4+2], xd = xv[iq*4+3];
        ac0.x += xa.x*w40.x + xb2.x*w40.y + xc.x*w40.z + xd.x*w40.w;
        ac0.y += xa.y*w40.x + xb2.y*w40.y + xc.y*w40.z + xd.y*w40.w;
        ac0.z += xa.z*w40.x + xb2.z*w40.y + xc.z*w40.z + xd.z*w40.w;
        ac0.w += xa.w*w40.x + xb2.w*w40.y + xc.w*w40.z + xd.w*w40.w;
        ac1.x += xa.x*w41.x + xb2.x*w41.y + xc.x*w41.z + xd.x*w41.w;
        ac1.y += xa.y*w41.x + xb2.y*w41.y + xc.y*w41.z + xd.y*w41.w;
        ac1.z += xa.z*w41.x + xb2.z*w41.y + xc.z*w41.z + xd.z*w41.w;
        ac1.w += xa.w*w41.x + xb2.w*w41.y + xc.w*w41.z + xd.w*w41.w;
      }
      // combine i-halves across the s-pair
      ac0.x += __shfl_xor(ac0.x, 1); ac0.y += __shfl_xor(ac0.y, 1);
      ac0.z += __shfl_xor(ac0.z, 1); ac0.w += __shfl_xor(ac0.w, 1);
      ac1.x += __shfl_xor(ac1.x, 1); ac1.y += __shfl_xor(ac1.y, 1);
      ac1.z += __shfl_xor(ac1.z, 1); ac1.w += __shfl_xor(ac1.w, 1);
      float4 r = (s == 0) ? ac0 : ac1;              // lane s owns o=s
      float4 bb = *(const float4*)(&bijL[s][c][n4 * 4]);
      r.x += bb.x; r.y += bb.y; r.z += bb.z; r.w += bb.w;
      *(float4*)(&bijL[s][c][n4 * 4]) = r;

      // per-wave max partials (parity-preserving: offsets 2..32)
      float m4 = fmaxf(fmaxf(r.x, r.y), fmaxf(r.z, r.w));
      #pragma unroll
      for (int off = 2; off <= 32; off <<= 1) m4 = fmaxf(m4, __shfl_xor(m4, off));
      int wave = tid >> 6;
      if ((tid & 63) <= 1) redM[wave][s] = m4;      // lane 0: o=0, lane 1: o=1
      __syncthreads();
      float mo = redM[0][s];                        // every thread reduces locally
      #pragma unroll
      for (int w2 = 1; w2 < CC; ++w2) mo = fmaxf(mo, redM[w2][s]);
      float ex = __expf(r.x - mo), ey = __expf(r.y - mo),
            ez = __expf(r.z - mo), ew = __expf(r.w - mo);
      float e = ex + ey + ez + ew;
      #pragma unroll
      for (int off = 2; off <= 32; off <<= 1) e += __shfl_xor(e, off);
      if ((tid & 63) <= 1) redE[wave][s] = e;
      __syncthreads();
      if (tid < 2) {                                // stats for next C
        float ss = 0.f, mm = redM[0][tid];
        #pragma unroll
        for (int w2 = 0; w2 < CC; ++w2) ss += redE[w2][tid];
        #pragma unroll
        for (int w2 = 1; w2 < CC; ++w2) mm = fmaxf(mm, redM[w2][tid]);
        smx[tid]  = mm;
        srin[tid] = 1.0f / ss;
      }
    }
    __syncthreads();
  }
}

extern "C" void kernel_launch(void* const* d_in, const int* in_sizes, int n_in,
                              void* d_out, int out_size, void* d_ws, size_t ws_size,
                              hipStream_t stream) {
  const float* x = (const float*)d_in[0];   // [B,N,C,I]
  const float* W = (const float*)d_in[1];   // [C,O,I,J]
  (void)in_sizes; (void)n_in;               // d_in[2] = number_of_nodes (fixed 128)
  float* out = (float*)d_out; (void)out_size;

  float* xT = (float*)d_ws;                 // 2,097,152 floats (8 MB), i-major
  (void)ws_size;

  k_transpose<<<BB * CC, 1024, 0, stream>>>(x, xT);
  k_route<<<BB * (OO / 2), 1024, 0, stream>>>(xT, W, out);
}

// Round 14
// 108.960 us; speedup vs baseline: 1.6594x; 1.1151x over previous
//
#include <hip/hip_runtime.h>
#include <math.h>

// Problem constants (fixed by the reference):
#define BB 32     // batch
#define NN 128    // nodes
#define CC 16     // in_ch
#define OO 32     // out_ch
#define II 32     // in_dim
#define JJ 32     // out_dim
#define MM (NN*CC)  // 2048 input capsules per (b, out_ch)
#define WP (JJ+1)   // padded Ws row: 33 floats -> conflict-free for BOTH
                    // A (lanes on j) and Wv (lanes on i, banks (i+j)%32)
static constexpr float EPS_ = 1e-11f;

// ROUND-14 = ROUND-11 (best verified: k_route 47 us) + barrier surgery.
// Round-13 lesson: U f4-reads exceeded the 64-VGPR wall -> 55 MB spill.
// U keeps round-11 scalar cw reads. The new lever is SYNCHRONIZATION:
// 7 -> 3 __syncthreads per iteration, by making producer/consumer pairs
// wave-aligned so the dependency is intra-wave (program order):
//   * A remapped to wave w <-> cA = w  -> C->A barrier deleted
//   * Wv remapped to wave w <-> cW = w -> Wv->U barrier deleted
//   * U stats: wave-local max m_w + local sum E_w, ONE barrier, then every
//     thread computes M and ss = sum_w E_w*exp(m_w-M) locally; mo/rin for
//     BOTH o's kept in registers via pair-lane shfl (smx/srin + loop-end
//     barrier deleted; redM/redE WAR is separated by BAR1 of next iter).
// Remaining barriers: BAR1 (A->squash, cross-wave partA), BAR2 (squash->
// Wv, vs), BAR3 (U stats). Spill tripwire: WRITE_SIZE must be ~8 MB.

// ---- one-time transpose: xT[b][c][i][n] = x[b][n][c][i] ----
__global__ __launch_bounds__(1024) void k_transpose(
    const float* __restrict__ x, float* __restrict__ xT) {
  int b = blockIdx.x >> 4, c = blockIdx.x & 15;
  __shared__ __align__(16) float xsT[II][NN + 4];   // +4: f4-aligned padded rows
  int tid = threadIdx.x;
  {
    int n = tid >> 3, i4 = (tid & 7) * 4;
    float4 v = *(const float4*)(x + (((size_t)(b * NN + n)) * CC + c) * II + i4);
    xsT[i4 + 0][n] = v.x; xsT[i4 + 1][n] = v.y;
    xsT[i4 + 2][n] = v.z; xsT[i4 + 3][n] = v.w;
  }
  __syncthreads();
  {
    int i = tid >> 5, n4 = tid & 31;
    float4 v = *(const float4*)(&xsT[i][n4 * 4]);   // row stride 528 B, 16B-aligned
    ((float4*)(xT + ((size_t)(b * CC + c)) * II * NN))[tid] = v;
  }
}

// 16-slot reduce-scatter across lane bits 1..4 (n4 bits); returns the
// fully-reduced value for slot qf = this lane's bit-pattern.
__device__ __forceinline__ float rs16(float p[16], int l) {
  bool u2 = (l >> 1) & 1, u4 = (l >> 2) & 1, u8 = (l >> 3) & 1, u16 = (l >> 4) & 1;
  #pragma unroll
  for (int k = 0; k < 8; ++k) {
    float s0 = u2 ? p[k] : p[k + 8];
    float r0 = __shfl_xor(s0, 2);
    p[k] = (u2 ? p[k + 8] : p[k]) + r0;
  }
  #pragma unroll
  for (int k = 0; k < 4; ++k) {
    float s0 = u4 ? p[k] : p[k + 4];
    float r0 = __shfl_xor(s0, 4);
    p[k] = (u4 ? p[k + 4] : p[k]) + r0;
  }
  #pragma unroll
  for (int k = 0; k < 2; ++k) {
    float s0 = u8 ? p[k] : p[k + 2];
    float r0 = __shfl_xor(s0, 8);
    p[k] = (u8 ? p[k + 2] : p[k]) + r0;
  }
  {
    float s0 = u16 ? p[0] : p[1];
    float r0 = __shfl_xor(s0, 16);
    p[0] = (u16 ? p[1] : p[0]) + r0;
  }
  p[0] += __shfl_xor(p[0], 32);          // allreduce the last n4 bit
  return p[0];
}

// ---- the whole routing loop. Block per (b, o-pair). 1024 threads. ----
__global__ __launch_bounds__(1024, 4) void k_route(
    const float* __restrict__ xT, const float* __restrict__ W,
    float* __restrict__ out) {
  int bid = blockIdx.x;
  int b = bid & 31, o0 = (bid >> 5) * 2;      // o-pair {o0, o0+1}
  int tid = threadIdx.x;

  __shared__ float Ws[CC * 2 * II * WP];            // 132 KB: W slice, padded
  __shared__ __align__(16) float bijL[2][CC][NN];   // 16 KB routing logits
  __shared__ __align__(16) float cw[2][CC][II];     // 4 KB: cxs in C/A, wv in Wv/U
  __shared__ float partA[2][CC][JJ];                // 4 KB
  __shared__ float vs[2][JJ];
  __shared__ float redM[CC][2], redE[CC][2];
  // total ~157 KB -> 1 block/CU

  // ---- stage W slice into LDS (once; W is iteration-invariant) ----
  {
    int q = tid & 7, r0 = tid >> 3;
    #pragma unroll
    for (int k = 0; k < 8; ++k) {
      int rowid = r0 + k * 128;                   // rowid = (c<<6)|(o<<5)|i
      int c = rowid >> 6, o = (rowid >> 5) & 1, i = rowid & 31;
      float4 v = *(const float4*)(W + ((((size_t)c * OO + o0 + o) * II + i) * JJ) + q * 4);
      float* dst = &Ws[rowid * WP + q * 4];       // coalesced 1KB/instr reads
      dst[0] = v.x; dst[1] = v.y; dst[2] = v.z; dst[3] = v.w;
    }
  }

  // x -> registers (once): thread (c, n4, s) owns i=s*16..s*16+15, n=n4*4..+3
  int l = tid & 63;
  int c = tid >> 6, n4 = l >> 1, s = l & 1;
  const float4* xTb = (const float4*)(xT + (size_t)b * CC * II * NN);
  const float4* xp  = xTb + c * (II * NN / 4) + (s * 16) * (NN / 4) + n4;
  float4 xv[16];
  #pragma unroll
  for (int q = 0; q < 16; ++q) xv[q] = xp[q * (NN / 4)];  // 512B runs, coalesced

  {  // init: bijL = 0
    int o = tid >> 9, ci = (tid >> 5) & 15, m4i = tid & 31;
    *(float4*)(&bijL[o][ci][m4i * 4]) = make_float4(0.f, 0.f, 0.f, 0.f);
  }
  // softmax stats in REGISTERS (per o); iter-0 uniform: mo=0, rin=1/MM
  float mo0 = 0.f, mo1 = 0.f;
  float rin0 = 1.0f / (float)MM, rin1 = rin0;
  __syncthreads();

  for (int it = 0; it < 3; ++it) {
    // --- C: cw[o][c][i] = sum_n coef(o,c,n)*x(c,n,i); coef recomputed
    //     from bijL + register stats (o's sequential) ---
    {
      int qf = ((l >> 1) & 1) * 8 + ((l >> 2) & 1) * 4
             + ((l >> 3) & 1) * 2 + ((l >> 4) & 1);
      #pragma unroll
      for (int o = 0; o < 2; ++o) {
        float4 bb = *(const float4*)(&bijL[o][c][n4 * 4]);
        float m  = (o == 0) ? mo0 : mo1;
        float ri = (o == 0) ? rin0 : rin1;
        float cfx = __expf(bb.x - m) * ri, cfy = __expf(bb.y - m) * ri;
        float cfz = __expf(bb.z - m) * ri, cfw = __expf(bb.w - m) * ri;
        float p[16];
        #pragma unroll
        for (int q = 0; q < 16; ++q)
          p[q] = xv[q].x*cfx + xv[q].y*cfy + xv[q].z*cfz + xv[q].w*cfw;
        float r = rs16(p, l);
        if ((l & 32) == 0) cw[o][c][s * 16 + qf] = r;
      }
    }
    // NO barrier: A below is wave-aligned with C's cw writes (wave w owns c=w)

    // --- A: partA[o][w][j] = sum_i cw[o][w][i] * Ws[w,o,i,j]  (pure LDS) ---
    {
      int cA = tid >> 6, o = (tid >> 5) & 1, j = tid & 31;
      const float* wsp = &Ws[((cA * 2 + o) * II) * WP + j];
      float acc = 0.f;
      #pragma unroll 8
      for (int i = 0; i < II; ++i)
        acc += cw[o][cA][i] * wsp[i * WP];   // cw half-wave broadcast
      partA[o][cA][j] = acc;
    }
    __syncthreads();                         // BAR1: squash needs all c

    // --- A-reduce + squash (final iter writes output) ---
    if (tid < 64) {
      int o = tid >> 5, j = tid & 31;
      float sA = 0.f;
      #pragma unroll
      for (int cR = 0; cR < CC; ++cR) sA += partA[o][cR][j];
      float msq = sA * sA;
      #pragma unroll
      for (int off = 16; off > 0; off >>= 1) msq += __shfl_xor(msq, off);
      float mag = sqrtf(msq) + EPS_;
      float a   = msq / (1.0f + msq);
      float vvq = a * sA / mag;
      if (it == 2) {
        int row = b * OO + (o0 + o);
        out[(size_t)row * JJ + j] = vvq;               // v_j: [B,1,O,J] flat
        if (j == 0) out[BB * OO * JJ + row] = a;       // a_j: [B,1,O,1] flat
      } else {
        vs[o][j] = vvq;
      }
    }
    if (it == 2) break;                   // uniform exit
    __syncthreads();                      // BAR2: Wv needs vs

    // --- Wv: cw[o][w][i] = sum_j Ws[w,o,i,j] * vs[o][j]  (pure LDS) ---
    {
      int cW = tid >> 6, o = (tid >> 5) & 1, i = tid & 31;
      const float* wsr = &Ws[((cW * 2 + o) * II + i) * WP];
      float acc = 0.f;
      #pragma unroll 8
      for (int j = 0; j < JJ; ++j)
        acc += wsr[j] * vs[o][j];          // banks (i+j)%32: conflict-free
      cw[o][cW][i] = acc;                  // buffer now holds wv
    }
    // NO barrier: U below is wave-aligned with Wv's cw writes (wave c)

    // --- U: bijL += x.wv (x regs, scalar cw broadcasts); 1-barrier stats ---
    {
      float4 ac0 = make_float4(0.f,0.f,0.f,0.f);
      float4 ac1 = make_float4(0.f,0.f,0.f,0.f);
      #pragma unroll
      for (int q = 0; q < 16; ++q) {
        int i = s * 16 + q;
        float w0 = cw[0][c][i], w1 = cw[1][c][i];   // 2-addr broadcasts
        ac0.x += xv[q].x * w0; ac0.y += xv[q].y * w0;
        ac0.z += xv[q].z * w0; ac0.w += xv[q].w * w0;
        ac1.x += xv[q].x * w1; ac1.y += xv[q].y * w1;
        ac1.z += xv[q].z * w1; ac1.w += xv[q].w * w1;
      }
      // combine i-halves across the s-pair
      ac0.x += __shfl_xor(ac0.x, 1); ac0.y += __shfl_xor(ac0.y, 1);
      ac0.z += __shfl_xor(ac0.z, 1); ac0.w += __shfl_xor(ac0.w, 1);
      ac1.x += __shfl_xor(ac1.x, 1); ac1.y += __shfl_xor(ac1.y, 1);
      ac1.z += __shfl_xor(ac1.z, 1); ac1.w += __shfl_xor(ac1.w, 1);
      float4 r = (s == 0) ? ac0 : ac1;              // lane s owns o=s
      float4 bb = *(const float4*)(&bijL[s][c][n4 * 4]);
      r.x += bb.x; r.y += bb.y; r.z += bb.z; r.w += bb.w;
      *(float4*)(&bijL[s][c][n4 * 4]) = r;

      // wave-local max + wave-local sum of exp(r - m_w), parity-preserving
      float m4 = fmaxf(fmaxf(r.x, r.y), fmaxf(r.z, r.w));
      #pragma unroll
      for (int off = 2; off <= 32; off <<= 1) m4 = fmaxf(m4, __shfl_xor(m4, off));
      float e = __expf(r.x - m4) + __expf(r.y - m4)
              + __expf(r.z - m4) + __expf(r.w - m4);
      #pragma unroll
      for (int off = 2; off <= 32; off <<= 1) e += __shfl_xor(e, off);
      int wave = tid >> 6;
      if ((tid & 63) <= 1) { redM[wave][s] = m4; redE[wave][s] = e; }
      __syncthreads();                    // BAR3: the only stats barrier
      // every thread: global max + rescaled sum for ITS parity s
      float mo = redM[0][s];
      #pragma unroll
      for (int w2 = 1; w2 < CC; ++w2) mo = fmaxf(mo, redM[w2][s]);
      float ss = 0.f;
      #pragma unroll
      for (int w2 = 0; w2 < CC; ++w2)
        ss += redE[w2][s] * __expf(redM[w2][s] - mo);
      float rin = 1.0f / ss;
      // pair-lane exchange gives the OTHER o's stats (lane l^1 has s^1)
      float moO = __shfl_xor(mo, 1), rinO = __shfl_xor(rin, 1);
      mo0  = (s == 0) ? mo  : moO;   mo1  = (s == 0) ? moO  : mo;
      rin0 = (s == 0) ? rin : rinO;  rin1 = (s == 0) ? rinO : rin;
      // no loop-end barrier: next C reads bijL/cw written by THIS wave;
      // redM/redE WAR vs next U is separated by next iter's BAR1.
    }
  }
}

extern "C" void kernel_launch(void* const* d_in, const int* in_sizes, int n_in,
                              void* d_out, int out_size, void* d_ws, size_t ws_size,
                              hipStream_t stream) {
  const float* x = (const float*)d_in[0];   // [B,N,C,I]
  const float* W = (const float*)d_in[1];   // [C,O,I,J]
  (void)in_sizes; (void)n_in;               // d_in[2] = number_of_nodes (fixed 128)
  float* out = (float*)d_out; (void)out_size;

  float* xT = (float*)d_ws;                 // 2,097,152 floats (8 MB), i-major
  (void)ws_size;

  k_transpose<<<BB * CC, 1024, 0, stream>>>(x, xT);
  k_route<<<BB * (OO / 2), 1024, 0, stream>>>(xT, W, out);
}